// Round 5
// baseline (150.776 us; speedup 1.0000x reference)
//
#include <hip/hip_runtime.h>
#include <hip/hip_bf16.h>

// Problem constants
#define L_ACT   12
#define BDIM    16
#define PDIM    128
#define DSUM    128
#define HID     512
#define ODIM    2048
#define NHEAD   16
#define DHEAD   64
#define MROWS   2048   // B*P rows per layer

typedef short short8 __attribute__((ext_vector_type(8)));
typedef float f32x4  __attribute__((ext_vector_type(4)));
typedef float f32x16 __attribute__((ext_vector_type(16)));

__device__ __forceinline__ void gload_lds16(const __hip_bfloat16* g, __hip_bfloat16* l) {
  __builtin_amdgcn_global_load_lds(
      (const __attribute__((address_space(1))) unsigned int*)g,
      (__attribute__((address_space(3))) unsigned int*)l, 16, 0, 0);
}

// --- zero-fill (fallback path only) ---
__global__ __launch_bounds__(256) void zerofill_kernel(f32x4* __restrict__ p, int n16) {
  int stride = gridDim.x * 256;
  for (int i = blockIdx.x * 256 + threadIdx.x; i < n16; i += stride)
    p[i] = {0.f, 0.f, 0.f, 0.f};
}

// --- transpose helper: f32 [J][O] tile -> bf16 [O][J] ---
__device__ __forceinline__ void transpose_tile(
    const float* __restrict__ ip, __hip_bfloat16* __restrict__ op,
    int J, int O, int o0, int j0, int tid) {
  __shared__ float t[32][33];
  int tx = tid & 31, ty = tid >> 5;   // 32x8
#pragma unroll
  for (int r = 0; r < 32; r += 8)
    t[ty + r][tx] = ip[(size_t)(j0 + ty + r) * O + o0 + tx];
  __syncthreads();
#pragma unroll
  for (int r = 0; r < 32; r += 8)
    op[(size_t)(o0 + ty + r) * J + j0 + tx] = __float2bfloat16(t[tx][ty + r]);
}

// --- prep_all: A_bf + cs | W1T | W2T, by blockIdx range ---
__global__ __launch_bounds__(256) void prep_all(
    const float* __restrict__ summary, const int* __restrict__ positions,
    const float* __restrict__ W1, const float* __restrict__ W2,
    __hip_bfloat16* __restrict__ A_bf, float* __restrict__ cs,
    __hip_bfloat16* __restrict__ W1T, __hip_bfloat16* __restrict__ W2T) {
  const int bid = blockIdx.x;
  const int tid = threadIdx.x;
  if (bid < 1024) {
    int i = bid * 256 + tid;            // covers 262144 exactly
    A_bf[i] = __float2bfloat16(summary[i]);
    if (i < PDIM * 8) {
      int p = i >> 3, f = i & 7;
      double inv = pow(10000.0, -(double)f / 8.0);
      double ang = (double)positions[p] * inv;
      cs[i]        = (float)cos(ang);
      cs[1024 + i] = (float)sin(ang);
    }
  } else if (bid < 1024 + 768) {
    int idx = bid - 1024;               // W1: [128][512] -> [512][128], 16x4 tiles x 12
    int bx = idx & 15, by = (idx >> 4) & 3, l = idx >> 6;
    transpose_tile(W1 + (size_t)l * DSUM * HID, W1T + (size_t)l * DSUM * HID,
                   DSUM, HID, bx * 32, by * 32, tid);
  } else {
    int idx = bid - 1792;               // W2: [512][2048] -> [2048][512], 64x16 tiles x 12
    int bx = idx & 63, by = (idx >> 6) & 15, l = idx >> 10;
    transpose_tile(W2 + (size_t)l * HID * ODIM, W2T + (size_t)l * HID * ODIM,
                   HID, ODIM, bx * 32, by * 32, tid);
  }
}

// --- GEMM1: 128x128 tile, 4 waves, bias+relu, bf16 out; optional fused
//     zero-fill of the inactive-layer region (768 x 256KB chunks, nt). ---
__global__ __launch_bounds__(256) void gemm1_128(
    const __hip_bfloat16* __restrict__ Aall,
    const __hip_bfloat16* __restrict__ Ball,
    const float* __restrict__ bias,
    __hip_bfloat16* __restrict__ Hall,
    f32x4* __restrict__ zeroBase, int doZero) {
  const int KTOT = DSUM, NTOT = HID;
  __shared__ __hip_bfloat16 ldsA[128 * 64];
  __shared__ __hip_bfloat16 ldsB[128 * 64];
  const int l    = blockIdx.z;
  const int n0   = blockIdx.x * 128;
  const int m0   = blockIdx.y * 128;
  const int tid  = threadIdx.x;
  const int wid  = tid >> 6;
  const int lane = tid & 63;
  const int wr = wid >> 1, wc = wid & 1;
  const __hip_bfloat16* A  = Aall;
  const __hip_bfloat16* Bt = Ball + (size_t)l * NTOT * KTOT;

  f32x4 acc[4][4];
#pragma unroll
  for (int m = 0; m < 4; ++m)
#pragma unroll
    for (int n = 0; n < 4; ++n)
      acc[m][n] = {0.f, 0.f, 0.f, 0.f};

  const int srowi = lane >> 3;
  const int sblk  = (lane & 7) ^ srowi;

  for (int kt = 0; kt < KTOT / 64; ++kt) {
    __syncthreads();
#pragma unroll
    for (int s = 0; s < 4; ++s) {
      int seg = wid * 4 + s;
      int row = seg * 8 + srowi;
      gload_lds16(A  + (size_t)(m0 + row) * KTOT + kt * 64 + sblk * 8, ldsA + seg * 512);
      gload_lds16(Bt + (size_t)(n0 + row) * KTOT + kt * 64 + sblk * 8, ldsB + seg * 512);
    }
    __syncthreads();
#pragma unroll
    for (int kk = 0; kk < 2; ++kk) {
      short8 af[4], bfr[4];
#pragma unroll
      for (int m = 0; m < 4; ++m) {
        int row = wr * 64 + m * 16 + (lane & 15);
        int off = (kk * 64 + (lane >> 4) * 16) ^ ((row & 7) << 4);
        af[m] = *(const short8*)((const char*)ldsA + row * 128 + off);
      }
#pragma unroll
      for (int n = 0; n < 4; ++n) {
        int row = wc * 64 + n * 16 + (lane & 15);
        int off = (kk * 64 + (lane >> 4) * 16) ^ ((row & 7) << 4);
        bfr[n] = *(const short8*)((const char*)ldsB + row * 128 + off);
      }
#pragma unroll
      for (int m = 0; m < 4; ++m)
#pragma unroll
        for (int n = 0; n < 4; ++n)
          acc[m][n] = __builtin_amdgcn_mfma_f32_16x16x32_bf16(af[m], bfr[n], acc[m][n], 0, 0, 0);
    }
  }

  if (doZero) {
    const f32x4 z = {0.f, 0.f, 0.f, 0.f};
    int chunk = blockIdx.x + 4 * blockIdx.y + 64 * blockIdx.z;   // 0..767
    f32x4* zp = zeroBase + (size_t)chunk * 16384;                // 256KB chunk
#pragma unroll
    for (int i = 0; i < 64; ++i)
      __builtin_nontemporal_store(z, zp + i * 256 + tid);
  }

  const int colBase = n0 + wc * 64 + (lane & 15);
  const int rowBase = m0 + wr * 64 + ((lane >> 4) << 2);
  __hip_bfloat16* H = Hall + (size_t)l * MROWS * HID;
#pragma unroll
  for (int n = 0; n < 4; ++n) {
    int col = colBase + n * 16;
    float bb = bias[l * NTOT + col];
#pragma unroll
    for (int m = 0; m < 4; ++m) {
      int row = rowBase + m * 16;
#pragma unroll
      for (int j = 0; j < 4; ++j) {
        float v = acc[m][n][j] + bb;
        v = v > 0.f ? v : 0.f;
        H[(size_t)(row + j) * HID + col] = __float2bfloat16(v);
      }
    }
  }
}

// --- GEMM2: 256x256 tile, 8 waves (2Mx4N), BK=32, 4-slot LDS ring,
//     fine-grained 2-phase/K-tile pipeline with counted vmcnt,
//     XCD-chunked tile swizzle, 32x32x16 MFMA, LDS-transpose epilogue
//     with nontemporal 1KB-contiguous slab stores. ---
__global__ __launch_bounds__(512, 1) void gemm2_pipe(
    const __hip_bfloat16* __restrict__ Aall,   // h_bf [12][2048][512]
    const __hip_bfloat16* __restrict__ Ball,   // W2T  [12][2048][512]
    const float* __restrict__ bias,            // b2   [12][2048]
    const float* __restrict__ cs,
    float* __restrict__ O) {
  __shared__ __hip_bfloat16 lds[4 * 16384];    // 128 KiB
  // XCD-chunked bijective swizzle: nwg = 8*8*12 = 768, 768 % 8 == 0.
  const int orig = blockIdx.x + 8 * blockIdx.y + 64 * blockIdx.z;
  const int nw   = (orig & 7) * 96 + (orig >> 3);
  const int bx   = nw & 7;
  const int by   = (nw >> 3) & 7;
  const int l    = nw >> 6;
  const int n0  = bx * 256;
  const int m0  = by * 256;
  const int tid = threadIdx.x;
  const int wid = tid >> 6, lane = tid & 63;
  const int wm  = wid >> 2, wn = wid & 3;
  const int hi  = lane >> 5;          // 0/1: k-half selector for 32x32 frags
  const int l31 = lane & 31;
  const __hip_bfloat16* A  = Aall + (size_t)l * MROWS * HID;
  const __hip_bfloat16* Bt = Ball + (size_t)l * ODIM * HID;

  f32x16 acc[4][2];                    // [msub][nsub], 32x32 each
#pragma unroll
  for (int m = 0; m < 4; ++m)
#pragma unroll
    for (int n = 0; n < 2; ++n)
      acc[m][n] = (f32x16)(0.f);

  const int cidx0 = wid * 128 + lane;
  const int cidx1 = cidx0 + 64;
  const int r0 = cidx0 >> 2, c0 = (cidx0 & 3) ^ ((r0 >> 1) & 3);
  const int r1 = cidx1 >> 2, c1 = (cidx1 & 3) ^ ((r1 >> 1) & 3);

#define STAGE_A(slot, kt) do {                                                      \
    gload_lds16(A + (size_t)(m0 + r0) * HID + (kt) * 32 + c0 * 8,                   \
                lds + (slot) * 16384 + wid * 1024);                                 \
    gload_lds16(A + (size_t)(m0 + r1) * HID + (kt) * 32 + c1 * 8,                   \
                lds + (slot) * 16384 + wid * 1024 + 512);                           \
  } while (0)
#define STAGE_B(slot, kt) do {                                                      \
    gload_lds16(Bt + (size_t)(n0 + r0) * HID + (kt) * 32 + c0 * 8,                  \
                lds + (slot) * 16384 + 8192 + wid * 1024);                          \
    gload_lds16(Bt + (size_t)(n0 + r1) * HID + (kt) * 32 + c1 * 8,                  \
                lds + (slot) * 16384 + 8192 + wid * 1024 + 512);                    \
  } while (0)

  // 32x32x16 fragment load: row = rowbase + (lane&31), wanted 16B chunk =
  // kh*2 + (lane>>5), stored at chunk ^ ((row>>1)&3).
#define LD32(dst, base, rowbase, kh) do {                                           \
    int r_ = (rowbase) + l31;                                                       \
    int c_ = (((kh) << 1) | hi) ^ ((r_ >> 1) & 3);                                  \
    dst = *(const short8*)((const char*)(base) + r_ * 64 + (c_ << 4));              \
  } while (0)

  // prologue: 3 tiles in flight
  STAGE_A(0, 0); STAGE_B(0, 0);
  STAGE_A(1, 1); STAGE_B(1, 1);
  STAGE_A(2, 2); STAGE_B(2, 2);
  asm volatile("s_waitcnt vmcnt(8)" ::: "memory");
  __builtin_amdgcn_s_barrier();

  const int NT = HID / 32;   // 16
  for (int t = 0; t < NT; ++t) {
    const __hip_bfloat16* sa = lds + (t & 3) * 16384;
    const __hip_bfloat16* sb = sa + 8192;
    short8 bfr[2][2], af[2][2];

    // ---- phase 0: msub 0,1 (+ all B-frags, reused in phase 1) ----
#pragma unroll
    for (int ns = 0; ns < 2; ++ns)
#pragma unroll
      for (int kh = 0; kh < 2; ++kh)
        LD32(bfr[ns][kh], sb, wn * 64 + ns * 32, kh);
#pragma unroll
    for (int ms = 0; ms < 2; ++ms)
#pragma unroll
      for (int kh = 0; kh < 2; ++kh)
        LD32(af[ms][kh], sa, wm * 128 + ms * 32, kh);
    if (t + 3 < NT) STAGE_A((t + 3) & 3, t + 3);
    __builtin_amdgcn_s_barrier();
    __builtin_amdgcn_s_setprio(1);
#pragma unroll
    for (int ms = 0; ms < 2; ++ms)
#pragma unroll
      for (int ns = 0; ns < 2; ++ns) {
        acc[ms][ns] = __builtin_amdgcn_mfma_f32_32x32x16_bf16(af[ms][0], bfr[ns][0], acc[ms][ns], 0, 0, 0);
        acc[ms][ns] = __builtin_amdgcn_mfma_f32_32x32x16_bf16(af[ms][1], bfr[ns][1], acc[ms][ns], 0, 0, 0);
      }
    __builtin_amdgcn_s_setprio(0);
    __builtin_amdgcn_s_barrier();

    // ---- phase 1: msub 2,3 ----
#pragma unroll
    for (int ms = 0; ms < 2; ++ms)
#pragma unroll
      for (int kh = 0; kh < 2; ++kh)
        LD32(af[ms][kh], sa, wm * 128 + 64 + ms * 32, kh);
    if (t + 3 < NT) STAGE_B((t + 3) & 3, t + 3);
    __builtin_amdgcn_s_barrier();
    __builtin_amdgcn_s_setprio(1);
#pragma unroll
    for (int ms = 0; ms < 2; ++ms)
#pragma unroll
      for (int ns = 0; ns < 2; ++ns) {
        acc[2 + ms][ns] = __builtin_amdgcn_mfma_f32_32x32x16_bf16(af[ms][0], bfr[ns][0], acc[2 + ms][ns], 0, 0, 0);
        acc[2 + ms][ns] = __builtin_amdgcn_mfma_f32_32x32x16_bf16(af[ms][1], bfr[ns][1], acc[2 + ms][ns], 0, 0, 0);
      }
    __builtin_amdgcn_s_setprio(0);
    if (t < NT - 1) {
      if (t <= NT - 4)      asm volatile("s_waitcnt vmcnt(8)" ::: "memory");
      else if (t == NT - 3) asm volatile("s_waitcnt vmcnt(4)" ::: "memory");
      else                  asm volatile("s_waitcnt vmcnt(0)" ::: "memory");
    }
    __builtin_amdgcn_s_barrier();
  }
#undef STAGE_A
#undef STAGE_B
#undef LD32

  // ---- epilogue: bias + RoPE in-reg, per-wave LDS transpose, nt 1KB stores ----
  __syncthreads();
  const int head = bx * 2 + (wn >> 1);
  const int tkv  = wn & 1;
  const int bidx = by * 2 + wm;
  float* slab = O + ((((size_t)(l + L_ACT) * 2 + tkv) * BDIM + bidx) * NHEAD + head) * (PDIM * DHEAD);
  const bool ropeWave = (tkv == 0);   // wn even; rope cols live in nsub 0, lanes (lane&31)<16

  float bb[2];
#pragma unroll
  for (int ns = 0; ns < 2; ++ns) bb[ns] = bias[l * ODIM + n0 + wn * 64 + ns * 32 + l31];

  float* Tw = (float*)lds + wid * 2080;   // 32 x 65 f32 per wave
  const int rl15 = lane & 15;

#pragma unroll
  for (int ms = 0; ms < 4; ++ms) {        // p-chunk [ms*32, ms*32+32)
#pragma unroll
    for (int ns = 0; ns < 2; ++ns) {
#pragma unroll
      for (int rg = 0; rg < 16; ++rg) {
        int rowLocal = (rg & 3) + 8 * (rg >> 2) + 4 * hi;
        float v = acc[ms][ns][rg] + bb[ns];
        if (ropeWave && ns == 0) {
          float partner = __shfl_xor(v, 8);
          int p = ms * 32 + rowLocal;
          float cv = cs[p * 8 + (lane & 7)];
          float sv = cs[1024 + p * 8 + (lane & 7)];
          float vr = v * cv + (((lane & 15) < 8) ? -partner : partner) * sv;
          v = (l31 < 16) ? vr : v;
        }
        Tw[rowLocal * 65 + ns * 32 + l31] = v;
      }
    }
#pragma unroll
    for (int it = 0; it < 8; ++it) {
      int pl = it * 4 + (lane >> 4);
      f32x4 vv = *(const f32x4*)(Tw + pl * 65 + rl15 * 4);
      __builtin_nontemporal_store(vv, (f32x4*)(slab + (size_t)(ms * 32 + pl) * DHEAD + rl15 * 4));
    }
  }
}

extern "C" void kernel_launch(void* const* d_in, const int* in_sizes, int n_in,
                              void* d_out, int out_size, void* d_ws, size_t ws_size,
                              hipStream_t stream) {
  const float* summary   = (const float*)d_in[0];
  const int*   positions = (const int*)d_in[1];
  const float* W1 = (const float*)d_in[2];
  const float* b1 = (const float*)d_in[3];
  const float* W2 = (const float*)d_in[4];
  const float* b2 = (const float*)d_in[5];
  float* out = (float*)d_out;

  const size_t SCRATCH_BYTES = 52436992;
  const bool useWs = (ws_size >= SCRATCH_BYTES);
  char* sc = useWs ? (char*)d_ws : (char*)d_out;
  __hip_bfloat16* h_bf = (__hip_bfloat16*)sc;                    // 25165824 B
  __hip_bfloat16* W2T  = (__hip_bfloat16*)(sc + 25165824);       // 25165824 B
  __hip_bfloat16* W1T  = (__hip_bfloat16*)(sc + 50331648);       // 1572864 B
  __hip_bfloat16* A_bf = (__hip_bfloat16*)(sc + 51904512);       // 524288 B
  float*          cs   = (float*)(sc + 52428800);                // 8192 B

  prep_all<<<14080, 256, 0, stream>>>(summary, positions, W1, W2, A_bf, cs, W1T, W2T);

  gemm1_128<<<dim3(HID / 128, MROWS / 128, L_ACT), 256, 0, stream>>>(
      A_bf, W1T, b1, h_bf, (f32x4*)d_out, useWs ? 1 : 0);
  gemm2_pipe<<<dim3(ODIM / 256, MROWS / 256, L_ACT), 512, 0, stream>>>(h_bf, W2T, b2, cs, out);

  if (!useWs)   // scratch aliased d_out: zero AFTER gemm2 has consumed it
    zerofill_kernel<<<2048, 256, 0, stream>>>((f32x4*)d_out, 12582912);
}

// Round 6
// 136.703 us; speedup vs baseline: 1.1029x; 1.1029x over previous
//
#include <hip/hip_runtime.h>
#include <hip/hip_bf16.h>

// Problem constants
#define L_ACT   12
#define BDIM    16
#define PDIM    128
#define DSUM    128
#define HID     512
#define ODIM    2048
#define NHEAD   16
#define DHEAD   64
#define MROWS   2048   // B*P rows per layer

typedef short short8 __attribute__((ext_vector_type(8)));
typedef float f32x4  __attribute__((ext_vector_type(4)));

__device__ __forceinline__ void gload_lds16(const __hip_bfloat16* g, __hip_bfloat16* l) {
  __builtin_amdgcn_global_load_lds(
      (const __attribute__((address_space(1))) unsigned int*)g,
      (__attribute__((address_space(3))) unsigned int*)l, 16, 0, 0);
}

// --- zero-fill (fallback path only) ---
__global__ __launch_bounds__(256) void zerofill_kernel(f32x4* __restrict__ p, int n16) {
  int stride = gridDim.x * 256;
  for (int i = blockIdx.x * 256 + threadIdx.x; i < n16; i += stride)
    p[i] = {0.f, 0.f, 0.f, 0.f};
}

// --- prep_small: A_bf + cs | W1T, by blockIdx range (W2T moved into gemm1) ---
__global__ __launch_bounds__(256) void prep_small(
    const float* __restrict__ summary, const int* __restrict__ positions,
    const float* __restrict__ W1,
    __hip_bfloat16* __restrict__ A_bf, float* __restrict__ cs,
    __hip_bfloat16* __restrict__ W1T) {
  const int bid = blockIdx.x;
  const int tid = threadIdx.x;
  if (bid < 1024) {
    int i = bid * 256 + tid;            // covers 262144 exactly
    A_bf[i] = __float2bfloat16(summary[i]);
    if (i < PDIM * 8) {
      int p = i >> 3, f = i & 7;
      double inv = pow(10000.0, -(double)f / 8.0);
      double ang = (double)positions[p] * inv;
      cs[i]        = (float)cos(ang);
      cs[1024 + i] = (float)sin(ang);
    }
  } else {
    __shared__ float t[32][33];
    int idx = bid - 1024;               // W1: [128][512] -> [512][128], 16x4 tiles x 12
    int bx = idx & 15, by = (idx >> 4) & 3, l = idx >> 6;
    int o0 = bx * 32, j0 = by * 32;
    int tx = tid & 31, ty = tid >> 5;   // 32x8
    const float* ip = W1 + (size_t)l * DSUM * HID;
#pragma unroll
    for (int r = 0; r < 32; r += 8)
      t[ty + r][tx] = ip[(size_t)(j0 + ty + r) * HID + o0 + tx];
    __syncthreads();
    __hip_bfloat16* op = W1T + (size_t)l * DSUM * HID;
#pragma unroll
    for (int r = 0; r < 32; r += 8)
      op[(size_t)(o0 + ty + r) * DSUM + j0 + tx] = __float2bfloat16(t[tx][ty + r]);
  }
}

// --- GEMM1: 128x128 tile, 4 waves, bias+relu, bf16 out; PLUS fused
//     zero-fill of the inactive-layer region (768 x 256KB chunks, nt)
//     and fused W2 -> W2T transpose (16 32x32 tiles per block). ---
__global__ __launch_bounds__(256) void gemm1_128(
    const __hip_bfloat16* __restrict__ Aall,
    const __hip_bfloat16* __restrict__ Ball,
    const float* __restrict__ bias,
    __hip_bfloat16* __restrict__ Hall,
    const float* __restrict__ W2,
    __hip_bfloat16* __restrict__ W2T,
    f32x4* __restrict__ zeroBase, int doZero) {
  const int KTOT = DSUM, NTOT = HID;
  __shared__ __hip_bfloat16 ldsA[128 * 64];
  __shared__ __hip_bfloat16 ldsB[128 * 64];
  const int l    = blockIdx.z;
  const int n0   = blockIdx.x * 128;
  const int m0   = blockIdx.y * 128;
  const int tid  = threadIdx.x;
  const int wid  = tid >> 6;
  const int lane = tid & 63;
  const int wr = wid >> 1, wc = wid & 1;
  const __hip_bfloat16* A  = Aall;
  const __hip_bfloat16* Bt = Ball + (size_t)l * NTOT * KTOT;

  f32x4 acc[4][4];
#pragma unroll
  for (int m = 0; m < 4; ++m)
#pragma unroll
    for (int n = 0; n < 4; ++n)
      acc[m][n] = {0.f, 0.f, 0.f, 0.f};

  const int srowi = lane >> 3;
  const int sblk  = (lane & 7) ^ srowi;

  for (int kt = 0; kt < KTOT / 64; ++kt) {
    __syncthreads();
#pragma unroll
    for (int s = 0; s < 4; ++s) {
      int seg = wid * 4 + s;
      int row = seg * 8 + srowi;
      gload_lds16(A  + (size_t)(m0 + row) * KTOT + kt * 64 + sblk * 8, ldsA + seg * 512);
      gload_lds16(Bt + (size_t)(n0 + row) * KTOT + kt * 64 + sblk * 8, ldsB + seg * 512);
    }
    __syncthreads();
#pragma unroll
    for (int kk = 0; kk < 2; ++kk) {
      short8 af[4], bfr[4];
#pragma unroll
      for (int m = 0; m < 4; ++m) {
        int row = wr * 64 + m * 16 + (lane & 15);
        int off = (kk * 64 + (lane >> 4) * 16) ^ ((row & 7) << 4);
        af[m] = *(const short8*)((const char*)ldsA + row * 128 + off);
      }
#pragma unroll
      for (int n = 0; n < 4; ++n) {
        int row = wc * 64 + n * 16 + (lane & 15);
        int off = (kk * 64 + (lane >> 4) * 16) ^ ((row & 7) << 4);
        bfr[n] = *(const short8*)((const char*)ldsB + row * 128 + off);
      }
#pragma unroll
      for (int m = 0; m < 4; ++m)
#pragma unroll
        for (int n = 0; n < 4; ++n)
          acc[m][n] = __builtin_amdgcn_mfma_f32_16x16x32_bf16(af[m], bfr[n], acc[m][n], 0, 0, 0);
    }
  }

  const int bid = blockIdx.x + 4 * blockIdx.y + 64 * blockIdx.z;   // 0..767

  // zero-fill chunk (nontemporal, fire-and-forget)
  if (doZero) {
    const f32x4 z = {0.f, 0.f, 0.f, 0.f};
    f32x4* zp = zeroBase + (size_t)bid * 16384;                    // 256KB chunk
#pragma unroll
    for (int i = 0; i < 64; ++i)
      __builtin_nontemporal_store(z, zp + i * 256 + tid);
  }

  // h epilogue
  const int colBase = n0 + wc * 64 + (lane & 15);
  const int rowBase = m0 + wr * 64 + ((lane >> 4) << 2);
  __hip_bfloat16* H = Hall + (size_t)l * MROWS * HID;
#pragma unroll
  for (int n = 0; n < 4; ++n) {
    int col = colBase + n * 16;
    float bb = bias[l * NTOT + col];
#pragma unroll
    for (int m = 0; m < 4; ++m) {
      int row = rowBase + m * 16;
#pragma unroll
      for (int j = 0; j < 4; ++j) {
        float v = acc[m][n][j] + bb;
        v = v > 0.f ? v : 0.f;
        H[(size_t)(row + j) * HID + col] = __float2bfloat16(v);
      }
    }
  }

  // fused W2 -> W2T transpose: 16 tiles of 32x32 per block (12288 total)
  {
    float* tb = (float*)ldsA;           // reuse 16KB LDS as 32x33 f32
    const int tx = tid & 31, ty = tid >> 5;
    const int tbase = bid * 16;
#pragma unroll 1
    for (int tt = 0; tt < 16; ++tt) {
      int t = tbase + tt;
      int lz = t >> 10, rem = t & 1023;
      int jt = rem >> 6, ot = rem & 63;   // 16 j-tiles x 64 o-tiles per layer
      int j0 = jt * 32, o0 = ot * 32;
      const float* ip = W2 + (size_t)lz * HID * ODIM;
      __hip_bfloat16* op = W2T + (size_t)lz * HID * ODIM;
      __syncthreads();
#pragma unroll
      for (int r = 0; r < 32; r += 8)
        tb[(ty + r) * 33 + tx] = ip[(size_t)(j0 + ty + r) * ODIM + o0 + tx];
      __syncthreads();
#pragma unroll
      for (int r = 0; r < 32; r += 8)
        op[(size_t)(o0 + ty + r) * HID + j0 + tx] = __float2bfloat16(tb[tx * 33 + ty + r]);
    }
  }
}

// --- GEMM2 (R4-proven): 256x256 tile, 8 waves (2Mx4N), BK=32, 4-slot LDS ring,
//     fine-grained 2-phase/K-tile pipeline with counted vmcnt, 16x16x32 MFMA,
//     XCD-chunked tile swizzle, LDS-transpose epilogue, nt 1KB slab stores. ---
__global__ __launch_bounds__(512, 1) void gemm2_pipe(
    const __hip_bfloat16* __restrict__ Aall,   // h_bf [12][2048][512]
    const __hip_bfloat16* __restrict__ Ball,   // W2T  [12][2048][512]
    const float* __restrict__ bias,            // b2   [12][2048]
    const float* __restrict__ cs,
    float* __restrict__ O) {
  __shared__ __hip_bfloat16 lds[4 * 16384];    // 128 KiB
  const int orig = blockIdx.x + 8 * blockIdx.y + 64 * blockIdx.z;
  const int nw   = (orig & 7) * 96 + (orig >> 3);
  const int bx   = nw & 7;
  const int by   = (nw >> 3) & 7;
  const int l    = nw >> 6;
  const int n0  = bx * 256;
  const int m0  = by * 256;
  const int tid = threadIdx.x;
  const int wid = tid >> 6, lane = tid & 63;
  const int wm  = wid >> 2, wn = wid & 3;
  const __hip_bfloat16* A  = Aall + (size_t)l * MROWS * HID;
  const __hip_bfloat16* Bt = Ball + (size_t)l * ODIM * HID;

  f32x4 acc[8][4];
#pragma unroll
  for (int m = 0; m < 8; ++m)
#pragma unroll
    for (int n = 0; n < 4; ++n)
      acc[m][n] = {0.f, 0.f, 0.f, 0.f};

  const int cidx0 = wid * 128 + lane;
  const int cidx1 = cidx0 + 64;
  const int r0 = cidx0 >> 2, c0 = (cidx0 & 3) ^ ((r0 >> 1) & 3);
  const int r1 = cidx1 >> 2, c1 = (cidx1 & 3) ^ ((r1 >> 1) & 3);

#define STAGE_A(slot, kt) do {                                                      \
    gload_lds16(A + (size_t)(m0 + r0) * HID + (kt) * 32 + c0 * 8,                   \
                lds + (slot) * 16384 + wid * 1024);                                 \
    gload_lds16(A + (size_t)(m0 + r1) * HID + (kt) * 32 + c1 * 8,                   \
                lds + (slot) * 16384 + wid * 1024 + 512);                           \
  } while (0)
#define STAGE_B(slot, kt) do {                                                      \
    gload_lds16(Bt + (size_t)(n0 + r0) * HID + (kt) * 32 + c0 * 8,                  \
                lds + (slot) * 16384 + 8192 + wid * 1024);                          \
    gload_lds16(Bt + (size_t)(n0 + r1) * HID + (kt) * 32 + c1 * 8,                  \
                lds + (slot) * 16384 + 8192 + wid * 1024 + 512);                    \
  } while (0)

  const int kq   = lane >> 4;
  const int rl15 = lane & 15;

#define LD_FRAG(dst, base, rr) do {                                                 \
    int r_ = (rr);                                                                  \
    int off_ = r_ * 64 + ((kq ^ ((r_ >> 1) & 3)) << 4);                             \
    dst = *(const short8*)((const char*)(base) + off_);                             \
  } while (0)

  // prologue: 3 tiles in flight
  STAGE_A(0, 0); STAGE_B(0, 0);
  STAGE_A(1, 1); STAGE_B(1, 1);
  STAGE_A(2, 2); STAGE_B(2, 2);
  asm volatile("s_waitcnt vmcnt(8)" ::: "memory");
  __builtin_amdgcn_s_barrier();

  const int NT = HID / 32;   // 16
  for (int t = 0; t < NT; ++t) {
    const __hip_bfloat16* sa = lds + (t & 3) * 16384;
    const __hip_bfloat16* sb = sa + 8192;
    short8 af[4], bfr[4];

    // ---- phase 0: m-frags 0..3 ----
#pragma unroll
    for (int n = 0; n < 4; ++n) LD_FRAG(bfr[n], sb, wn * 64 + n * 16 + rl15);
#pragma unroll
    for (int mi = 0; mi < 4; ++mi) LD_FRAG(af[mi], sa, wm * 128 + mi * 16 + rl15);
    if (t + 3 < NT) STAGE_A((t + 3) & 3, t + 3);
    __builtin_amdgcn_s_barrier();
    __builtin_amdgcn_s_setprio(1);
#pragma unroll
    for (int mi = 0; mi < 4; ++mi)
#pragma unroll
      for (int n = 0; n < 4; ++n)
        acc[mi][n] = __builtin_amdgcn_mfma_f32_16x16x32_bf16(af[mi], bfr[n], acc[mi][n], 0, 0, 0);
    __builtin_amdgcn_s_setprio(0);
    __builtin_amdgcn_s_barrier();

    // ---- phase 1: m-frags 4..7 (bfr reused) ----
#pragma unroll
    for (int mi = 0; mi < 4; ++mi) LD_FRAG(af[mi], sa, wm * 128 + 64 + mi * 16 + rl15);
    if (t + 3 < NT) STAGE_B((t + 3) & 3, t + 3);
    __builtin_amdgcn_s_barrier();
    __builtin_amdgcn_s_setprio(1);
#pragma unroll
    for (int mi = 0; mi < 4; ++mi)
#pragma unroll
      for (int n = 0; n < 4; ++n)
        acc[4 + mi][n] = __builtin_amdgcn_mfma_f32_16x16x32_bf16(af[mi], bfr[n], acc[4 + mi][n], 0, 0, 0);
    __builtin_amdgcn_s_setprio(0);
    if (t < NT - 1) {
      if (t <= NT - 4)      asm volatile("s_waitcnt vmcnt(8)" ::: "memory");
      else if (t == NT - 3) asm volatile("s_waitcnt vmcnt(4)" ::: "memory");
      else                  asm volatile("s_waitcnt vmcnt(0)" ::: "memory");
    }
    __builtin_amdgcn_s_barrier();
  }
#undef STAGE_A
#undef STAGE_B
#undef LD_FRAG

  // ---- epilogue: bias + RoPE in-reg, per-wave LDS transpose, nt 1KB stores ----
  __syncthreads();
  const int head = bx * 2 + (wn >> 1);
  const int tkv  = wn & 1;
  const int bidx = by * 2 + wm;
  float* slab = O + ((((size_t)(l + L_ACT) * 2 + tkv) * BDIM + bidx) * NHEAD + head) * (PDIM * DHEAD);
  const bool ropeWave = (tkv == 0);

  float bb[4];
#pragma unroll
  for (int n = 0; n < 4; ++n) bb[n] = bias[l * ODIM + n0 + wn * 64 + n * 16 + rl15];

  float* Tw = (float*)lds + wid * 2080;   // 32 x 65 f32 per wave

#pragma unroll
  for (int c = 0; c < 4; ++c) {           // p-chunk [c*32, c*32+32)
#pragma unroll
    for (int mh = 0; mh < 2; ++mh) {
      int mf = c * 2 + mh;
      int pl = mh * 16 + (lane >> 4) * 4;
#pragma unroll
      for (int n = 0; n < 4; ++n) {
#pragma unroll
        for (int j = 0; j < 4; ++j) {
          float v = acc[mf][n][j] + bb[n];
          if (ropeWave && n == 0) {
            float partner = __shfl_xor(v, 8);
            int p = c * 32 + pl + j;
            float cv = cs[p * 8 + (lane & 7)];
            float sv = cs[1024 + p * 8 + (lane & 7)];
            v = v * cv + (((lane & 15) < 8) ? -partner : partner) * sv;
          }
          Tw[(pl + j) * 65 + n * 16 + rl15] = v;
        }
      }
    }
#pragma unroll
    for (int it = 0; it < 8; ++it) {
      int pl = it * 4 + (lane >> 4);
      f32x4 vv = *(const f32x4*)(Tw + pl * 65 + rl15 * 4);
      __builtin_nontemporal_store(vv, (f32x4*)(slab + (size_t)(c * 32 + pl) * DHEAD + rl15 * 4));
    }
  }
}

extern "C" void kernel_launch(void* const* d_in, const int* in_sizes, int n_in,
                              void* d_out, int out_size, void* d_ws, size_t ws_size,
                              hipStream_t stream) {
  const float* summary   = (const float*)d_in[0];
  const int*   positions = (const int*)d_in[1];
  const float* W1 = (const float*)d_in[2];
  const float* b1 = (const float*)d_in[3];
  const float* W2 = (const float*)d_in[4];
  const float* b2 = (const float*)d_in[5];
  float* out = (float*)d_out;

  const size_t SCRATCH_BYTES = 52436992;
  const bool useWs = (ws_size >= SCRATCH_BYTES);
  char* sc = useWs ? (char*)d_ws : (char*)d_out;
  __hip_bfloat16* h_bf = (__hip_bfloat16*)sc;                    // 25165824 B
  __hip_bfloat16* W2T  = (__hip_bfloat16*)(sc + 25165824);       // 25165824 B
  __hip_bfloat16* W1T  = (__hip_bfloat16*)(sc + 50331648);       // 1572864 B
  __hip_bfloat16* A_bf = (__hip_bfloat16*)(sc + 51904512);       // 524288 B
  float*          cs   = (float*)(sc + 52428800);                // 8192 B

  prep_small<<<1792, 256, 0, stream>>>(summary, positions, W1, A_bf, cs, W1T);

  gemm1_128<<<dim3(HID / 128, MROWS / 128, L_ACT), 256, 0, stream>>>(
      A_bf, W1T, b1, h_bf, W2, W2T, (f32x4*)d_out, useWs ? 1 : 0);
  gemm2_pipe<<<dim3(ODIM / 256, MROWS / 256, L_ACT), 512, 0, stream>>>(h_bf, W2T, b2, cs, out);

  if (!useWs)   // scratch aliased d_out: zero AFTER gemm2 has consumed it
    zerofill_kernel<<<2048, 256, 0, stream>>>((f32x4*)d_out, 12582912);
}